// Round 1
// baseline (838.108 us; speedup 1.0000x reference)
//
#include <hip/hip_runtime.h>
#include <math.h>

// Problem constants
constexpr int CBS   = 8;
constexpr int CN    = 1024;
constexpr int CFIN  = 256;
constexpr int CNH   = 8;
constexpr int CFOUT = 64;

// ---------------------------------------------------------------------------
// Kernel 1: h_prime[b,h,n,o] = sum_k h[b,n,k] * w[h,k,o]   (f32)
//           t = tanh(h_prime); attn_src[b,h,n] = sum_o t*a_src[h,o]; same dst
// Block: 256 threads = 4 waves; 16 rows per block (4 rows per wave).
// LDS: w[h] fully staged (64KB) + 16 h rows (16KB) = 80KB -> 2 blocks/CU.
// ---------------------------------------------------------------------------
__global__ __launch_bounds__(256) void gat_hprime(
    const float* __restrict__ h, const float* __restrict__ w,
    const float* __restrict__ a_src, const float* __restrict__ a_dst,
    float* __restrict__ hp, float* __restrict__ vsrc, float* __restrict__ vdst) {
  __shared__ float w_s[CFIN * CFOUT];   // [k][o], 64KB
  __shared__ float h_s[16 * CFIN];      // [row][k], 16KB

  const int t    = threadIdx.x;
  const int blk  = blockIdx.x;          // ((b*8)+head)*64 + tile
  const int tile = blk & 63;
  const int head = (blk >> 6) & 7;
  const int b    = blk >> 9;
  const int n0   = tile * 16;

  // stage w[head] : 16384 floats, 16 float4 per thread, coalesced
  const float* wg = w + (size_t)head * CFIN * CFOUT;
  #pragma unroll
  for (int i = 0; i < 16; ++i) {
    int idx = (i * 256 + t) * 4;
    *(float4*)(w_s + idx) = *(const float4*)(wg + idx);
  }
  // stage 16 h rows : 4096 floats, 4 float4 per thread, coalesced
  const float* hg = h + ((size_t)b * CN + n0) * CFIN;
  #pragma unroll
  for (int i = 0; i < 4; ++i) {
    int idx = (i * 256 + t) * 4;
    *(float4*)(h_s + idx) = *(const float4*)(hg + idx);
  }
  __syncthreads();

  const int o = t & 63, wid = t >> 6;
  float acc[4] = {0.f, 0.f, 0.f, 0.f};

  for (int k = 0; k < CFIN; k += 4) {
    // w reads: lane o, stride-64 floats -> 2 lanes/bank, conflict-free
    float w0 = w_s[(k + 0) * CFOUT + o];
    float w1 = w_s[(k + 1) * CFOUT + o];
    float w2 = w_s[(k + 2) * CFOUT + o];
    float w3 = w_s[(k + 3) * CFOUT + o];
    #pragma unroll
    for (int q = 0; q < 4; ++q) {
      float4 hv = *(const float4*)(h_s + (wid * 4 + q) * CFIN + k);  // broadcast
      acc[q] = fmaf(hv.x, w0, acc[q]);
      acc[q] = fmaf(hv.y, w1, acc[q]);
      acc[q] = fmaf(hv.z, w2, acc[q]);
      acc[q] = fmaf(hv.w, w3, acc[q]);
    }
  }

  const size_t bh = (size_t)b * CNH + head;
  const float asv = a_src[head * CFOUT + o];
  const float adv = a_dst[head * CFOUT + o];
  #pragma unroll
  for (int q = 0; q < 4; ++q) {
    int n = n0 + wid * 4 + q;
    float v = acc[q];
    hp[(bh * CN + n) * CFOUT + o] = v;        // coalesced
    float tv = tanhf(v);
    float vs = tv * asv, vd = tv * adv;
    for (int mm = 32; mm; mm >>= 1) {
      vs += __shfl_xor(vs, mm, 64);
      vd += __shfl_xor(vd, mm, 64);
    }
    if (o == 0) { vsrc[bh * CN + n] = vs; vdst[bh * CN + n] = vd; }
  }
}

// ---------------------------------------------------------------------------
// Kernel 2: masked online-softmax + PV.
// Block: 256 threads = 4 waves; each wave owns 4 query rows.
// Chunk of 64 j's: lane acts as j for score/exp (coalesced adj+dst loads),
// then lane acts as o for PV with __shfl broadcast of e (coalesced hp loads).
// ---------------------------------------------------------------------------
__global__ __launch_bounds__(256) void gat_attn(
    const int* __restrict__ adj, const float* __restrict__ hp,
    const float* __restrict__ vsrc, const float* __restrict__ vdst,
    float* __restrict__ out) {
  const int t    = threadIdx.x;
  const int lane = t & 63, wid = t >> 6;
  const int blk  = blockIdx.x;
  const int tile = blk & 63;
  const int head = (blk >> 6) & 7;
  const int b    = blk >> 9;
  const size_t bh = (size_t)b * CNH + head;
  const int i0 = tile * 16 + wid * 4;

  const int*   adjb = adj + (size_t)b * CN * CN;
  const float* dstp = vdst + bh * CN;
  const float* hpb  = hp + bh * CN * CFOUT;

  float src[4], m[4], l[4], acc[4];
  #pragma unroll
  for (int r = 0; r < 4; ++r) {
    src[r] = vsrc[bh * CN + i0 + r];
    m[r] = -INFINITY; l[r] = 0.f; acc[r] = 0.f;
  }

  for (int jt = 0; jt < CN; jt += 64) {
    const int jl = jt + lane;
    const float dv = dstp[jl];
    float e[4];
    #pragma unroll
    for (int r = 0; r < 4; ++r) {
      int a = adjb[(size_t)(i0 + r) * CN + jl];
      float s = src[r] + dv;
      s = s >= 0.f ? s : 0.2f * s;            // leaky_relu(0.2)
      float sv = (a > 0) ? s : -INFINITY;
      float cm = sv;
      for (int mm = 32; mm; mm >>= 1) cm = fmaxf(cm, __shfl_xor(cm, mm, 64));
      float mn = fmaxf(m[r], cm);
      if (mn > -1e37f) {                       // at least one valid j so far
        float scale = __expf(m[r] - mn);       // m=-inf -> 0 (acc,l are 0)
        acc[r] *= scale; l[r] *= scale;
        m[r] = mn;
        e[r] = __expf(sv - mn);                // masked: exp(-inf)=0
        l[r] += e[r];                          // per-lane partial sum
      } else {
        e[r] = 0.f;
      }
    }
    // PV: lane = o, broadcast e across lanes
    const float* hpc = hpb + (size_t)jt * CFOUT + lane;
    #pragma unroll
    for (int jj = 0; jj < 64; ++jj) {
      float hv = hpc[jj * CFOUT];              // coalesced 256B/wave
      acc[0] = fmaf(__shfl(e[0], jj, 64), hv, acc[0]);
      acc[1] = fmaf(__shfl(e[1], jj, 64), hv, acc[1]);
      acc[2] = fmaf(__shfl(e[2], jj, 64), hv, acc[2]);
      acc[3] = fmaf(__shfl(e[3], jj, 64), hv, acc[3]);
    }
  }

  #pragma unroll
  for (int r = 0; r < 4; ++r) {
    float ls = l[r];
    for (int mm = 32; mm; mm >>= 1) ls += __shfl_xor(ls, mm, 64);
    out[(bh * CN + i0 + r) * CFOUT + lane] = acc[r] / ls;
  }
}

extern "C" void kernel_launch(void* const* d_in, const int* in_sizes, int n_in,
                              void* d_out, int out_size, void* d_ws, size_t ws_size,
                              hipStream_t stream) {
  const float* h     = (const float*)d_in[0];
  const int*   adj   = (const int*)d_in[1];
  const float* w     = (const float*)d_in[2];
  const float* a_src = (const float*)d_in[3];
  const float* a_dst = (const float*)d_in[4];
  float* out = (float*)d_out;

  // ws layout: hp (BS*NH*N*FOUT f32 = 16MB) | vsrc (256KB) | vdst (256KB)
  float* hp = (float*)d_ws;
  float* vs = hp + (size_t)CBS * CNH * CN * CFOUT;
  float* vd = vs + (size_t)CBS * CNH * CN;

  hipLaunchKernelGGL(gat_hprime, dim3(CBS * CNH * (CN / 16)), dim3(256), 0, stream,
                     h, w, a_src, a_dst, hp, vs, vd);
  hipLaunchKernelGGL(gat_attn, dim3(CBS * CNH * (CN / 16)), dim3(256), 0, stream,
                     adj, hp, vs, vd, out);
}

// Round 2
// 195.400 us; speedup vs baseline: 4.2892x; 4.2892x over previous
//
#include <hip/hip_runtime.h>
#include <math.h>

constexpr int CBS   = 8;
constexpr int CN    = 1024;
constexpr int CFIN  = 256;
constexpr int CNH   = 8;
constexpr int CFOUT = 64;

using f32x4 = __attribute__((ext_vector_type(4))) float;
using s16x8 = __attribute__((ext_vector_type(8))) short;

__device__ __forceinline__ short f2bf(float x) {
  __bf16 b = (__bf16)x;
  return __builtin_bit_cast(short, b);
}
__device__ __forceinline__ float bf2f(short s) {
  __bf16 b = __builtin_bit_cast(__bf16, s);
  return (float)b;
}

// ---------------------------------------------------------------------------
// Kernel 1 (unchanged from round 1): hp = h@w (f32 VALU), vsrc/vdst via tanh
// ---------------------------------------------------------------------------
__global__ __launch_bounds__(256) void gat_hprime(
    const float* __restrict__ h, const float* __restrict__ w,
    const float* __restrict__ a_src, const float* __restrict__ a_dst,
    float* __restrict__ hp, float* __restrict__ vsrc, float* __restrict__ vdst) {
  __shared__ float w_s[CFIN * CFOUT];
  __shared__ float h_s[16 * CFIN];

  const int t    = threadIdx.x;
  const int blk  = blockIdx.x;
  const int tile = blk & 63;
  const int head = (blk >> 6) & 7;
  const int b    = blk >> 9;
  const int n0   = tile * 16;

  const float* wg = w + (size_t)head * CFIN * CFOUT;
  #pragma unroll
  for (int i = 0; i < 16; ++i) {
    int idx = (i * 256 + t) * 4;
    *(float4*)(w_s + idx) = *(const float4*)(wg + idx);
  }
  const float* hg = h + ((size_t)b * CN + n0) * CFIN;
  #pragma unroll
  for (int i = 0; i < 4; ++i) {
    int idx = (i * 256 + t) * 4;
    *(float4*)(h_s + idx) = *(const float4*)(hg + idx);
  }
  __syncthreads();

  const int o = t & 63, wid = t >> 6;
  float acc[4] = {0.f, 0.f, 0.f, 0.f};

  for (int k = 0; k < CFIN; k += 4) {
    float w0 = w_s[(k + 0) * CFOUT + o];
    float w1 = w_s[(k + 1) * CFOUT + o];
    float w2 = w_s[(k + 2) * CFOUT + o];
    float w3 = w_s[(k + 3) * CFOUT + o];
    #pragma unroll
    for (int q = 0; q < 4; ++q) {
      float4 hv = *(const float4*)(h_s + (wid * 4 + q) * CFIN + k);
      acc[q] = fmaf(hv.x, w0, acc[q]);
      acc[q] = fmaf(hv.y, w1, acc[q]);
      acc[q] = fmaf(hv.z, w2, acc[q]);
      acc[q] = fmaf(hv.w, w3, acc[q]);
    }
  }

  const size_t bh = (size_t)b * CNH + head;
  const float asv = a_src[head * CFOUT + o];
  const float adv = a_dst[head * CFOUT + o];
  #pragma unroll
  for (int q = 0; q < 4; ++q) {
    int n = n0 + wid * 4 + q;
    float v = acc[q];
    hp[(bh * CN + n) * CFOUT + o] = v;
    float tv = tanhf(v);
    float vs = tv * asv, vd = tv * adv;
    for (int mm = 32; mm; mm >>= 1) {
      vs += __shfl_xor(vs, mm, 64);
      vd += __shfl_xor(vd, mm, 64);
    }
    if (o == 0) { vsrc[bh * CN + n] = vs; vdst[bh * CN + n] = vd; }
  }
}

// ---------------------------------------------------------------------------
// Kernel 2: pack adj (int32 0/1) into a bitmask: 1 bit per (b,i,j). u64 words.
// ---------------------------------------------------------------------------
__global__ __launch_bounds__(256) void pack_adj(
    const int* __restrict__ adj, unsigned long long* __restrict__ mask) {
  const int t = threadIdx.x, lane = t & 63, w = t >> 6;
  const long long wid = (long long)blockIdx.x * 4 + w;   // (b*1024+i)*16 + jw
  const int jw = (int)(wid & 15);
  const long long bi = wid >> 4;
  int a = adj[bi * 1024 + jw * 64 + lane];
  unsigned long long m = __ballot(a > 0);
  if (lane == 0) mask[wid] = m;
}

// ---------------------------------------------------------------------------
// Kernel 3: split hp (f32, [bh][n][o]) into hi/lo bf16 TRANSPOSED [bh][o][n].
// LDS tile transpose, 64x64 per block.
// ---------------------------------------------------------------------------
__global__ __launch_bounds__(256) void split_T(
    const float* __restrict__ hp, short* __restrict__ hiT, short* __restrict__ loT) {
  __shared__ float s[64 * 65];
  const int blk = blockIdx.x;       // bh*16 + ntile
  const int nt = blk & 15, bh = blk >> 4;
  const int n0 = nt * 64;
  const int t = threadIdx.x;
  const float* src = hp + ((size_t)bh * CN + n0) * CFOUT;
  #pragma unroll
  for (int p = 0; p < 16; ++p) {
    int r = p * 4 + (t >> 6), o = t & 63;
    s[o * 65 + r] = src[(size_t)r * CFOUT + o];
  }
  __syncthreads();
  #pragma unroll
  for (int p = 0; p < 8; ++p) {
    int o = p * 8 + (t >> 5);
    int np = (t & 31) * 2;
    float v0 = s[o * 65 + np], v1 = s[o * 65 + np + 1];
    short h0 = f2bf(v0), h1 = f2bf(v1);
    short l0 = f2bf(v0 - bf2f(h0)), l1 = f2bf(v1 - bf2f(h1));
    size_t base = ((size_t)bh * CFOUT + o) * CN + n0 + np;   // even
    ((unsigned int*)hiT)[base >> 1] =
        (unsigned int)(unsigned short)h0 | ((unsigned int)(unsigned short)h1 << 16);
    ((unsigned int*)loT)[base >> 1] =
        (unsigned int)(unsigned short)l0 | ((unsigned int)(unsigned short)l1 << 16);
  }
}

// ---------------------------------------------------------------------------
// Kernel 4: masked-exp GEMM via MFMA.
// out[i,o] = sum_j e_ij * hp[j,o] / sum_j e_ij,  e_ij = 2^(LR(src+dst)*K - C*K)
// Wave: 32 i-rows x 64 o. A (P) generated in-register in fragment layout:
//   A[m][k]: lane l -> m = l&15, k = (l>>4)*8 + r   (16x16x32 bf16)
//   B[k][n]: lane l -> n = l&15, k = (l>>4)*8 + r   (from hpT[o][j], contiguous)
//   C[m][n]: lane l -> n(col) = l&15, m(row) = (l>>4)*4 + q   [verified layout]
// Splitting: P = ph+pl, V = vh+vl; out ≈ ph*vh + ph*vl + pl*vh.
// ---------------------------------------------------------------------------
__global__ __launch_bounds__(256) void gat_attn_mfma(
    const unsigned int* __restrict__ mask32,
    const short* __restrict__ hiT, const short* __restrict__ loT,
    const float* __restrict__ vsrc, const float* __restrict__ vdst,
    float* __restrict__ out) {
  const int t = threadIdx.x, lane = t & 63, w = t >> 6;
  const int blk = blockIdx.x;           // bh*8 + tile128
  const int bh = blk >> 3;
  const int b  = bh >> 3;
  const int i0 = (blk & 7) * 128 + w * 32;
  const int l15 = lane & 15, g4 = lane >> 4;
  const float LOG2E = 1.44269504088896340736f;

  const float* dstp = vdst + (size_t)bh * CN;

  // wave-level M = max_j dst_j  (upper bound for row max after LR shift)
  float M = -INFINITY;
  #pragma unroll
  for (int s_ = 0; s_ < 16; ++s_) M = fmaxf(M, dstp[s_ * 64 + lane]);
  for (int mm = 32; mm; mm >>= 1) M = fmaxf(M, __shfl_xor(M, mm, 64));

  float srcK[2], CK[2];
  #pragma unroll
  for (int f = 0; f < 2; ++f) {
    float sv = vsrc[(size_t)bh * CN + i0 + f * 16 + l15];
    float c = sv + M;
    c = fmaxf(c, 0.2f * c);            // C_i = LR(src_i + M) >= row max
    srcK[f] = sv * LOG2E;
    CK[f]   = c * LOG2E;
  }

  f32x4 acc[2][4];
  #pragma unroll
  for (int f = 0; f < 2; ++f)
    #pragma unroll
    for (int g = 0; g < 4; ++g) acc[f][g] = (f32x4){0.f, 0.f, 0.f, 0.f};
  float lsum[2] = {0.f, 0.f};

  const unsigned int* mrow0 = mask32 + ((size_t)b * CN + i0 + l15) * 32;
  const unsigned int* mrow1 = mrow0 + 16 * 32;
  const short* Bh = hiT + ((size_t)bh * CFOUT + l15) * CN + g4 * 8;
  const short* Bl = loT + ((size_t)bh * CFOUT + l15) * CN + g4 * 8;

  for (int j0 = 0; j0 < CN; j0 += 32) {
    // dst for this lane's 8 k-slots (broadcast across the 16-lane group)
    const float* dj = dstp + j0 + g4 * 8;
    float dK[8];
    {
      float4 d0 = *(const float4*)&dj[0];
      float4 d1 = *(const float4*)&dj[4];
      dK[0] = d0.x * LOG2E; dK[1] = d0.y * LOG2E; dK[2] = d0.z * LOG2E; dK[3] = d0.w * LOG2E;
      dK[4] = d1.x * LOG2E; dK[5] = d1.y * LOG2E; dK[6] = d1.z * LOG2E; dK[7] = d1.w * LOG2E;
    }
    // B fragments (hi/lo), contiguous 16B per lane from hpT
    s16x8 bhf[4], blf[4];
    #pragma unroll
    for (int g = 0; g < 4; ++g) {
      bhf[g] = *(const s16x8*)(Bh + (size_t)g * 16 * CN + j0);
      blf[g] = *(const s16x8*)(Bl + (size_t)g * 16 * CN + j0);
    }
    // A fragments: generate P in-register
    s16x8 ph[2], pl[2];
    #pragma unroll
    for (int f = 0; f < 2; ++f) {
      unsigned int word = (f ? mrow1 : mrow0)[j0 >> 5];
      unsigned int byte = (word >> (g4 * 8)) & 0xFFu;
      float sK = srcK[f], cK = CK[f];
      float ls = 0.f;
      #pragma unroll
      for (int r = 0; r < 8; ++r) {
        float s2 = sK + dK[r];
        float lr = fmaxf(s2, 0.2f * s2);     // LR in log2-scaled domain (K>0)
        float e = exp2f(lr - cK);
        e = (byte & (1u << r)) ? e : 0.f;
        ls += e;
        short hi = f2bf(e);
        ph[f][r] = hi;
        pl[f][r] = f2bf(e - bf2f(hi));
      }
      lsum[f] += ls;
    }
    // 24 MFMAs: 2 i-frags x 4 o-frags x 3 split products
    #pragma unroll
    for (int f = 0; f < 2; ++f)
      #pragma unroll
      for (int g = 0; g < 4; ++g) {
        acc[f][g] = __builtin_amdgcn_mfma_f32_16x16x32_bf16(ph[f], bhf[g], acc[f][g], 0, 0, 0);
        acc[f][g] = __builtin_amdgcn_mfma_f32_16x16x32_bf16(ph[f], blf[g], acc[f][g], 0, 0, 0);
        acc[f][g] = __builtin_amdgcn_mfma_f32_16x16x32_bf16(pl[f], bhf[g], acc[f][g], 0, 0, 0);
      }
  }

  // reduce l across the 4 lane-groups (same row lives at lanes l15+16g)
  #pragma unroll
  for (int f = 0; f < 2; ++f) {
    lsum[f] += __shfl_xor(lsum[f], 16, 64);
    lsum[f] += __shfl_xor(lsum[f], 32, 64);
  }

  #pragma unroll
  for (int f = 0; f < 2; ++f) {
    float linv[4];
    #pragma unroll
    for (int q = 0; q < 4; ++q)
      linv[q] = 1.0f / __shfl(lsum[f], g4 * 4 + q, 64);   // lane r holds row r's l
    #pragma unroll
    for (int g = 0; g < 4; ++g)
      #pragma unroll
      for (int q = 0; q < 4; ++q) {
        int row = i0 + f * 16 + g4 * 4 + q;
        int col = g * 16 + l15;
        out[((size_t)bh * CN + row) * CFOUT + col] = acc[f][g][q] * linv[q];
      }
  }
}

extern "C" void kernel_launch(void* const* d_in, const int* in_sizes, int n_in,
                              void* d_out, int out_size, void* d_ws, size_t ws_size,
                              hipStream_t stream) {
  const float* h     = (const float*)d_in[0];
  const int*   adj   = (const int*)d_in[1];
  const float* w     = (const float*)d_in[2];
  const float* a_src = (const float*)d_in[3];
  const float* a_dst = (const float*)d_in[4];
  float* out = (float*)d_out;

  // ws layout (all 16B aligned):
  // hp   f32  [64][1024][64]  16 MB
  // hiT  bf16 [64][64][1024]   8 MB
  // loT  bf16 [64][64][1024]   8 MB
  // vsrc f32  [64][1024]     256 KB
  // vdst f32  [64][1024]     256 KB
  // mask u64  [8*1024*16]      1 MB
  char* p = (char*)d_ws;
  float* hp  = (float*)p;                 p += (size_t)64 * CN * CFOUT * 4;
  short* hiT = (short*)p;                 p += (size_t)64 * CFOUT * CN * 2;
  short* loT = (short*)p;                 p += (size_t)64 * CFOUT * CN * 2;
  float* vs  = (float*)p;                 p += (size_t)64 * CN * 4;
  float* vd  = (float*)p;                 p += (size_t)64 * CN * 4;
  unsigned long long* mask = (unsigned long long*)p;

  hipLaunchKernelGGL(gat_hprime, dim3(CBS * CNH * (CN / 16)), dim3(256), 0, stream,
                     h, w, a_src, a_dst, hp, vs, vd);
  hipLaunchKernelGGL(pack_adj, dim3(CBS * CN * 16 / 4), dim3(256), 0, stream,
                     adj, mask);
  hipLaunchKernelGGL(split_T, dim3(64 * 16), dim3(256), 0, stream,
                     hp, hiT, loT);
  hipLaunchKernelGGL(gat_attn_mfma, dim3(64 * 8), dim3(256), 0, stream,
                     (const unsigned int*)mask, hiT, loT, vs, vd, out);
}